// Round 5
// baseline (1260.412 us; speedup 1.0000x reference)
//
#include <hip/hip_runtime.h>
#include <hip/hip_bf16.h>

typedef __hip_bfloat16 bf16;
typedef short v8s __attribute__((ext_vector_type(8)));     // 8 bf16 (4 VGPRs)
typedef float f32x4 __attribute__((ext_vector_type(4)));   // MFMA acc

#define B_  32
#define L_  144
#define D_  96
#define HW_ 64

// main kernel geometry
#define PXROW 22                 // (16+6) patch rows/cols
#define PIXSTRIDE 80             // 32 l * 2B = 64B data + 16B pad (bank spread)
#define NPATCH (PXROW*PXROW*32)  // staged elements per l-chunk
#define WPACK_ELEMS (83*5*96*32) // packed bf16 weights

__device__ __forceinline__ unsigned short f2bf(float f) {
    union { float f; unsigned int u; } x{f};
    unsigned int r = x.u + 0x7fffu + ((x.u >> 16) & 1u);   // RNE
    return (unsigned short)(r >> 16);
}

// ---------------------------------------------------------------------------
// Weight prep: pack w1/w2/w3 (fp32, [D][L][k][k]) into A-fragment order bf16:
// wpack[((T*5+q)*96 + d)*32 + l~],  T: 0..48=7x7 taps, 49..73=5x5, 74..82=3x3,
// q = l-chunk (l = q*32+l~, zero-padded past 143).
// ---------------------------------------------------------------------------
__global__ __launch_bounds__(256) void prep_weights(
    const float* __restrict__ w1, const float* __restrict__ w2,
    const float* __restrict__ w3, unsigned short* __restrict__ wpack)
{
    int i = blockIdx.x * 256 + threadIdx.x;
    if (i >= WPACK_ELEMS) return;
    const int lt = i & 31;
    const int d  = (i >> 5) % 96;
    const int r  = (i >> 5) / 96;   // T*5 + q
    const int q  = r % 5;
    const int T  = r / 5;
    const int l  = q * 32 + lt;
    float v = 0.f;
    if (l < L_) {
        if (T < 49)      v = w3[(d * L_ + l) * 49 + T];
        else if (T < 74) v = w2[(d * L_ + l) * 25 + (T - 49)];
        else             v = w1[(d * L_ + l) * 9  + (T - 74)];
    }
    wpack[i] = f2bf(v);
}

// ---------------------------------------------------------------------------
// MFMA branch conv v2 (occupancy-focused): 48 d per block (gridDim.z = 2),
// 1024 threads = 16 waves; wave = 3 d-tiles x 1 px-row x 3 branches = 9 accs
// (36 acc regs vs 144 in v1 -> 4 waves/SIMD instead of 2).
// Emits add/max bf16 planes packed into d_out (as before).
// ---------------------------------------------------------------------------
__global__ __launch_bounds__(1024, 4) void branch_conv_mfma(
    const float* __restrict__ x, const unsigned short* __restrict__ wpack,
    const float* __restrict__ b1, const float* __restrict__ g1,
    const float* __restrict__ be1, const float* __restrict__ m1,
    const float* __restrict__ v1,
    const float* __restrict__ b2, const float* __restrict__ g2,
    const float* __restrict__ be2, const float* __restrict__ m2,
    const float* __restrict__ v2,
    const float* __restrict__ b3, const float* __restrict__ g3,
    const float* __restrict__ be3, const float* __restrict__ m3,
    const float* __restrict__ v3,
    float* __restrict__ outp)
{
    __shared__ __align__(16) unsigned char patchB[PXROW * PXROW * PIXSTRIDE]; // 38720 B
    __shared__ float bns[48 * 6];

    const int t    = threadIdx.x;
    const int lane = t & 63;
    const int wid  = t >> 6;           // 0..15 : output row within 16x16 tile
    const int lo = lane & 15;
    const int hi = lane >> 4;          // 0..3

    const int st = blockIdx.x;         // spatial tile 0..15
    const int h0 = (st >> 2) << 4;
    const int w0 = (st & 3) << 4;
    const int b  = blockIdx.y;
    const int dz = blockIdx.z;         // 0..1 : d-half (48 d)

    // per-lane fragment offsets
    const int laneBoff = lo * PIXSTRIDE + hi * 16;         // bytes into patch pixel row
    const int laneAoff = lo * 32 + hi * 8;                 // elements into wpack block

    // BN constants for this block's 48 d -> LDS (visible after first barrier)
    if (t < 48) {
        const int d = dz * 48 + t;
        const float i1 = g1[d] * rsqrtf(v1[d] + 1e-5f);
        const float i2 = g2[d] * rsqrtf(v2[d] + 1e-5f);
        const float i3 = g3[d] * rsqrtf(v3[d] + 1e-5f);
        bns[t*6+0] = i1; bns[t*6+1] = fmaf(b1[d] - m1[d], i1, be1[d]);
        bns[t*6+2] = i2; bns[t*6+3] = fmaf(b2[d] - m2[d], i2, be2[d]);
        bns[t*6+4] = i3; bns[t*6+5] = fmaf(b3[d] - m3[d], i3, be3[d]);
    }

    f32x4 acc3[3], acc2[3], acc1[3];
    #pragma unroll
    for (int dt = 0; dt < 3; ++dt) {
        acc3[dt] = (f32x4)0.f; acc2[dt] = (f32x4)0.f; acc1[dt] = (f32x4)0.f;
    }

    // wave-invariant weight base: + q*3072 per chunk, + T*15360 per tap
    const unsigned short* wqBase = wpack + dz * 1536 + laneAoff;

    for (int q = 0; q < 5; ++q) {
        __syncthreads();
        // ---- stage patch chunk q: [pixel][32 l] bf16, 80B pixel stride ----
        for (int i = t; i < NPATCH; i += 1024) {
            const int l   = i / 484;          // 0..31
            const int pix = i - l * 484;
            const int r = pix / PXROW, c = pix - r * PXROW;
            const int gh = h0 - 3 + r, gw = w0 - 3 + c;
            const int lg = q * 32 + l;
            float v = 0.f;
            if (lg < L_ && (unsigned)gh < 64u && (unsigned)gw < 64u)
                v = x[(((size_t)b * L_ + lg) << 12) + (gh << 6) + gw];
            *(unsigned short*)(patchB + pix * PIXSTRIDE + l * 2) = f2bf(v);
        }
        __syncthreads();

        const unsigned short* wq = wqBase + q * 3072;

        for (int kh = 0; kh < 7; ++kh) {
            const int rb0 = (wid + kh) * PXROW;
            #pragma unroll
            for (int kw = 0; kw < 7; ++kw) {
                // B fragment: this wave's single px-row, shared across branches
                const v8s Bv = *(const v8s*)(patchB + (rb0 + kw) * PIXSTRIDE + laneBoff);

                // ---- branch 3 (7x7): every tap ----
                {
                    const unsigned short* wp = wq + (kh * 7 + kw) * 15360;
                    const v8s A0 = *(const v8s*)(wp);
                    const v8s A1 = *(const v8s*)(wp + 512);
                    const v8s A2 = *(const v8s*)(wp + 1024);
                    acc3[0] = __builtin_amdgcn_mfma_f32_16x16x32_bf16(A0, Bv, acc3[0], 0, 0, 0);
                    acc3[1] = __builtin_amdgcn_mfma_f32_16x16x32_bf16(A1, Bv, acc3[1], 0, 0, 0);
                    acc3[2] = __builtin_amdgcn_mfma_f32_16x16x32_bf16(A2, Bv, acc3[2], 0, 0, 0);
                }
                // ---- branch 2 (5x5): central 5x5 taps ----
                if (kh >= 1 && kh <= 5 && kw >= 1 && kw <= 5) {
                    const unsigned short* wp = wq + (49 + (kh - 1) * 5 + (kw - 1)) * 15360;
                    const v8s A0 = *(const v8s*)(wp);
                    const v8s A1 = *(const v8s*)(wp + 512);
                    const v8s A2 = *(const v8s*)(wp + 1024);
                    acc2[0] = __builtin_amdgcn_mfma_f32_16x16x32_bf16(A0, Bv, acc2[0], 0, 0, 0);
                    acc2[1] = __builtin_amdgcn_mfma_f32_16x16x32_bf16(A1, Bv, acc2[1], 0, 0, 0);
                    acc2[2] = __builtin_amdgcn_mfma_f32_16x16x32_bf16(A2, Bv, acc2[2], 0, 0, 0);
                }
                // ---- branch 1 (3x3): central 3x3 taps ----
                if (kh >= 2 && kh <= 4 && kw >= 2 && kw <= 4) {
                    const unsigned short* wp = wq + (74 + (kh - 2) * 3 + (kw - 2)) * 15360;
                    const v8s A0 = *(const v8s*)(wp);
                    const v8s A1 = *(const v8s*)(wp + 512);
                    const v8s A2 = *(const v8s*)(wp + 1024);
                    acc1[0] = __builtin_amdgcn_mfma_f32_16x16x32_bf16(A0, Bv, acc1[0], 0, 0, 0);
                    acc1[1] = __builtin_amdgcn_mfma_f32_16x16x32_bf16(A1, Bv, acc1[1], 0, 0, 0);
                    acc1[2] = __builtin_amdgcn_mfma_f32_16x16x32_bf16(A2, Bv, acc1[2], 0, 0, 0);
                }
            }
        }
    }

    // ---- epilogue: BN+ReLU per branch, add & max, pack bf16 into d_out ----
    // C/D layout: col = lane&15 (pixel), row = hi*4 + reg (d within tile)
    #pragma unroll
    for (int dt = 0; dt < 3; ++dt) {
        #pragma unroll
        for (int reg = 0; reg < 4; ++reg) {
            const int dl = dt * 16 + hi * 4 + reg;       // local d 0..47
            const int d  = dz * 48 + dl;
            const float i1 = bns[dl*6+0], c1 = bns[dl*6+1];
            const float i2 = bns[dl*6+2], c2 = bns[dl*6+3];
            const float i3 = bns[dl*6+4], c3 = bns[dl*6+5];
            unsigned short* pl = (unsigned short*)(outp + (((size_t)b * D_ + d) << 12));
            const float y1 = fmaxf(0.f, fmaf(acc1[dt][reg], i1, c1));
            const float y2 = fmaxf(0.f, fmaf(acc2[dt][reg], i2, c2));
            const float y3 = fmaxf(0.f, fmaf(acc3[dt][reg], i3, c3));
            const float av = y1 + y2 + y3;
            const float mv = fmaxf(y1, fmaxf(y2, y3));
            const int h = h0 + wid;
            const int idx = (h << 6) + w0 + lo;
            pl[idx]        = f2bf(av);
            pl[4096 + idx] = f2bf(mv);
        }
    }
}

// ---------------------------------------------------------------------------
// Kernel B: per-plane 3x3 conv over [add; max] with avg folded (unchanged).
// ---------------------------------------------------------------------------
__global__ __launch_bounds__(256) void fuse_kernel(
    const float* __restrict__ wf, float* __restrict__ out)
{
    const int p = blockIdx.x;      // plane = b*96 + d
    const int t = threadIdx.x;
    __shared__ float sa[66 * 66];
    __shared__ float sm[66 * 66];
    const bf16* base = (const bf16*)(out + ((size_t)p << 12));

    for (int i = t; i < 66 * 66; i += 256) {
        const int c = i % 66, r = i / 66;
        const int gh = r - 1, gw = c - 1;
        float va = 0.f, vm = 0.f;
        if (gh >= 0 && gh < 64 && gw >= 0 && gw < 64) {
            va = __bfloat162float(base[(gh << 6) + gw]);
            vm = __bfloat162float(base[4096 + (gh << 6) + gw]);
        }
        sa[i] = va; sm[i] = vm;
    }

    float wa[9], wm[9];
    #pragma unroll
    for (int j = 0; j < 9; ++j) {
        wa[j] = wf[j] + wf[9 + j] * (1.f / 3.f);
        wm[j] = wf[18 + j];
    }
    __syncthreads();

    float* op = out + ((size_t)p << 12);
    for (int i = t; i < 4096; i += 256) {
        const int h = i >> 6, w = i & 63;
        float acc = 0.f;
        #pragma unroll
        for (int kh = 0; kh < 3; ++kh) {
            #pragma unroll
            for (int kw = 0; kw < 3; ++kw) {
                acc = fmaf(sa[(h + kh) * 66 + (w + kw)], wa[kh * 3 + kw], acc);
                acc = fmaf(sm[(h + kh) * 66 + (w + kw)], wm[kh * 3 + kw], acc);
            }
        }
        op[i] = acc;
    }
}

extern "C" void kernel_launch(void* const* d_in, const int* in_sizes, int n_in,
                              void* d_out, int out_size, void* d_ws, size_t ws_size,
                              hipStream_t stream)
{
    const float* x   = (const float*)d_in[0];
    const float* w1  = (const float*)d_in[1];
    const float* b1  = (const float*)d_in[2];
    const float* g1  = (const float*)d_in[3];
    const float* be1 = (const float*)d_in[4];
    const float* m1  = (const float*)d_in[5];
    const float* v1  = (const float*)d_in[6];
    const float* w2  = (const float*)d_in[7];
    const float* b2  = (const float*)d_in[8];
    const float* g2  = (const float*)d_in[9];
    const float* be2 = (const float*)d_in[10];
    const float* m2  = (const float*)d_in[11];
    const float* v2  = (const float*)d_in[12];
    const float* w3  = (const float*)d_in[13];
    const float* b3  = (const float*)d_in[14];
    const float* g3  = (const float*)d_in[15];
    const float* be3 = (const float*)d_in[16];
    const float* m3  = (const float*)d_in[17];
    const float* v3  = (const float*)d_in[18];
    const float* wf  = (const float*)d_in[19];
    float* out = (float*)d_out;

    // d_ws: packed bf16 weights, 83*5*96*32*2B = 2.55 MB (rewritten every call)
    unsigned short* wpack = (unsigned short*)d_ws;

    prep_weights<<<(WPACK_ELEMS + 255) / 256, 256, 0, stream>>>(w1, w2, w3, wpack);

    dim3 gridA(16, B_, 2);   // 16 spatial tiles x 32 batch x 2 d-halves
    branch_conv_mfma<<<gridA, 1024, 0, stream>>>(
        x, wpack,
        b1, g1, be1, m1, v1,
        b2, g2, be2, m2, v2,
        b3, g3, be3, m3, v3,
        out);

    fuse_kernel<<<B_ * D_, 256, 0, stream>>>(wf, out);
}

// Round 6
// 541.505 us; speedup vs baseline: 2.3276x; 2.3276x over previous
//
#include <hip/hip_runtime.h>
#include <hip/hip_bf16.h>

typedef __hip_bfloat16 bf16;
typedef short v8s __attribute__((ext_vector_type(8)));     // 8 bf16 (4 VGPRs)
typedef float f32x4 __attribute__((ext_vector_type(4)));   // MFMA acc

#define B_  32
#define L_  144
#define D_  96
#define HW_ 64

// geometry (v1 = round-4 proven 650us structure)
#define PXROW 22                 // (16+6) patch rows/cols
#define PIXSTRIDE 80             // 32 l * 2B = 64B data + 16B pad (bank spread)
#define NPATCH (PXROW*PXROW*32)  // staged elements per l-chunk
#define WPACK_ELEMS (83*5*96*32) // packed bf16 weights

__device__ __forceinline__ unsigned short f2bf(float f) {
    union { float f; unsigned int u; } x{f};
    unsigned int r = x.u + 0x7fffu + ((x.u >> 16) & 1u);   // RNE
    return (unsigned short)(r >> 16);
}

// ---------------------------------------------------------------------------
// Weight prep: pack w1/w2/w3 (fp32, [D][L][k][k]) into A-fragment order bf16:
// wpack[((T*5+q)*96 + d)*32 + l~],  T: 0..48=7x7 taps, 49..73=5x5, 74..82=3x3,
// q = l-chunk (l = q*32+l~, zero-padded past 143).
// ---------------------------------------------------------------------------
__global__ __launch_bounds__(256) void prep_weights(
    const float* __restrict__ w1, const float* __restrict__ w2,
    const float* __restrict__ w3, unsigned short* __restrict__ wpack)
{
    int i = blockIdx.x * 256 + threadIdx.x;
    if (i >= WPACK_ELEMS) return;
    const int lt = i & 31;
    const int d  = (i >> 5) % 96;
    const int r  = (i >> 5) / 96;   // T*5 + q
    const int q  = r % 5;
    const int T  = r / 5;
    const int l  = q * 32 + lt;
    float v = 0.f;
    if (l < L_) {
        if (T < 49)      v = w3[(d * L_ + l) * 49 + T];
        else if (T < 74) v = w2[(d * L_ + l) * 25 + (T - 49)];
        else             v = w1[(d * L_ + l) * 9  + (T - 74)];
    }
    wpack[i] = f2bf(v);
}

// ---------------------------------------------------------------------------
// K7: 7x7 branch conv only. v1 geometry: 96d x (16x16 px) block, 8 waves
// (2 d-halves x 4 px-quads), wave = 3 d-tiles x 4 px-tiles x 1 branch
// = 12 accs. BN3+ReLU applied; y3 written bf16 into the plane slot's upper
// half (elements [4096..8192) of the 16KB slot), to be consumed by K53.
// ---------------------------------------------------------------------------
__global__ __launch_bounds__(512, 4) void k7_conv(
    const float* __restrict__ x, const unsigned short* __restrict__ wpack,
    const float* __restrict__ b3, const float* __restrict__ g3,
    const float* __restrict__ be3, const float* __restrict__ m3,
    const float* __restrict__ v3,
    float* __restrict__ outp)
{
    __shared__ __align__(16) unsigned char patchB[PXROW * PXROW * PIXSTRIDE];
    __shared__ float bns[96 * 2];

    const int t    = threadIdx.x;
    const int lane = t & 63;
    const int wid  = t >> 6;           // 0..7
    const int dhalf = wid >> 2;        // 0..1
    const int ptb   = (wid & 3) * 4;   // px-quad base row
    const int lo = lane & 15;
    const int hi = lane >> 4;

    const int st = blockIdx.x;
    const int h0 = (st >> 2) << 4;
    const int w0 = (st & 3) << 4;
    const int b  = blockIdx.y;

    const int laneBoff = lo * PIXSTRIDE + hi * 16;
    const int laneAoff = lo * 32 + hi * 8;

    if (t < 96) {
        const float i3 = g3[t] * rsqrtf(v3[t] + 1e-5f);
        bns[t*2+0] = i3;
        bns[t*2+1] = fmaf(b3[t] - m3[t], i3, be3[t]);
    }

    f32x4 acc[3][4];
    #pragma unroll
    for (int dt = 0; dt < 3; ++dt)
        #pragma unroll
        for (int pp = 0; pp < 4; ++pp) acc[dt][pp] = (f32x4)0.f;

    const unsigned short* wqBase = wpack + dhalf * 1536 + laneAoff;

    for (int q = 0; q < 5; ++q) {
        __syncthreads();
        for (int i = t; i < NPATCH; i += 512) {
            const int l   = i / 484;
            const int pix = i - l * 484;
            const int r = pix / PXROW, c = pix - r * PXROW;
            const int gh = h0 - 3 + r, gw = w0 - 3 + c;
            const int lg = q * 32 + l;
            float v = 0.f;
            if (lg < L_ && (unsigned)gh < 64u && (unsigned)gw < 64u)
                v = x[(((size_t)b * L_ + lg) << 12) + (gh << 6) + gw];
            *(unsigned short*)(patchB + pix * PIXSTRIDE + l * 2) = f2bf(v);
        }
        __syncthreads();

        const unsigned short* wq = wqBase + q * 3072;

        for (int kh = 0; kh < 7; ++kh) {
            const int rb0 = (ptb + kh) * PXROW;
            #pragma unroll
            for (int kw = 0; kw < 7; ++kw) {
                v8s Bv[4];
                #pragma unroll
                for (int pp = 0; pp < 4; ++pp)
                    Bv[pp] = *(const v8s*)(patchB + (rb0 + pp * PXROW + kw) * PIXSTRIDE + laneBoff);

                const unsigned short* wp = wq + (kh * 7 + kw) * 15360;
                const v8s A0 = *(const v8s*)(wp);
                const v8s A1 = *(const v8s*)(wp + 512);
                const v8s A2 = *(const v8s*)(wp + 1024);
                #pragma unroll
                for (int pp = 0; pp < 4; ++pp) {
                    acc[0][pp] = __builtin_amdgcn_mfma_f32_16x16x32_bf16(A0, Bv[pp], acc[0][pp], 0, 0, 0);
                    acc[1][pp] = __builtin_amdgcn_mfma_f32_16x16x32_bf16(A1, Bv[pp], acc[1][pp], 0, 0, 0);
                    acc[2][pp] = __builtin_amdgcn_mfma_f32_16x16x32_bf16(A2, Bv[pp], acc[2][pp], 0, 0, 0);
                }
            }
        }
    }

    // epilogue: BN3 + ReLU, store y3 bf16 to slot upper half
    #pragma unroll
    for (int dt = 0; dt < 3; ++dt) {
        #pragma unroll
        for (int reg = 0; reg < 4; ++reg) {
            const int d = dhalf * 48 + dt * 16 + hi * 4 + reg;
            const float i3 = bns[d*2+0], c3 = bns[d*2+1];
            unsigned short* pl = (unsigned short*)(outp + (((size_t)b * D_ + d) << 12));
            #pragma unroll
            for (int pp = 0; pp < 4; ++pp) {
                const float y3 = fmaxf(0.f, fmaf(acc[dt][pp][reg], i3, c3));
                const int idx = ((h0 + ptb + pp) << 6) + w0 + lo;
                pl[4096 + idx] = f2bf(y3);
            }
        }
    }
}

// ---------------------------------------------------------------------------
// K53: 5x5 + 3x3 branches (share B-frags on central taps). Same geometry,
// 24 accs. Epilogue: y1,y2 from accs (BN+ReLU), y3 read from slot upper
// half, add -> slot[0..4096), mx -> slot[4096..8192) (overwrites y3 after
// read; same-thread same-px ownership).
// ---------------------------------------------------------------------------
__global__ __launch_bounds__(512, 3) void k53_conv(
    const float* __restrict__ x, const unsigned short* __restrict__ wpack,
    const float* __restrict__ b1, const float* __restrict__ g1,
    const float* __restrict__ be1, const float* __restrict__ m1,
    const float* __restrict__ v1,
    const float* __restrict__ b2, const float* __restrict__ g2,
    const float* __restrict__ be2, const float* __restrict__ m2,
    const float* __restrict__ v2,
    float* __restrict__ outp)
{
    __shared__ __align__(16) unsigned char patchB[PXROW * PXROW * PIXSTRIDE];
    __shared__ float bns[96 * 4];

    const int t    = threadIdx.x;
    const int lane = t & 63;
    const int wid  = t >> 6;
    const int dhalf = wid >> 2;
    const int ptb   = (wid & 3) * 4;
    const int lo = lane & 15;
    const int hi = lane >> 4;

    const int st = blockIdx.x;
    const int h0 = (st >> 2) << 4;
    const int w0 = (st & 3) << 4;
    const int b  = blockIdx.y;

    const int laneBoff = lo * PIXSTRIDE + hi * 16;
    const int laneAoff = lo * 32 + hi * 8;

    if (t < 96) {
        const float i1 = g1[t] * rsqrtf(v1[t] + 1e-5f);
        const float i2 = g2[t] * rsqrtf(v2[t] + 1e-5f);
        bns[t*4+0] = i1; bns[t*4+1] = fmaf(b1[t] - m1[t], i1, be1[t]);
        bns[t*4+2] = i2; bns[t*4+3] = fmaf(b2[t] - m2[t], i2, be2[t]);
    }

    f32x4 acc2[3][4], acc1[3][4];
    #pragma unroll
    for (int dt = 0; dt < 3; ++dt)
        #pragma unroll
        for (int pp = 0; pp < 4; ++pp) { acc2[dt][pp] = (f32x4)0.f; acc1[dt][pp] = (f32x4)0.f; }

    const unsigned short* wqBase = wpack + dhalf * 1536 + laneAoff;

    for (int q = 0; q < 5; ++q) {
        __syncthreads();
        for (int i = t; i < NPATCH; i += 512) {
            const int l   = i / 484;
            const int pix = i - l * 484;
            const int r = pix / PXROW, c = pix - r * PXROW;
            const int gh = h0 - 3 + r, gw = w0 - 3 + c;
            const int lg = q * 32 + l;
            float v = 0.f;
            if (lg < L_ && (unsigned)gh < 64u && (unsigned)gw < 64u)
                v = x[(((size_t)b * L_ + lg) << 12) + (gh << 6) + gw];
            *(unsigned short*)(patchB + pix * PIXSTRIDE + l * 2) = f2bf(v);
        }
        __syncthreads();

        const unsigned short* wq = wqBase + q * 3072;

        // 5x5 tap walk; 5x5 tap (kh5,kw5) sits at 7x7 offset (kh5+1, kw5+1)
        for (int kh5 = 0; kh5 < 5; ++kh5) {
            const int rb0 = (ptb + kh5 + 1) * PXROW;
            #pragma unroll
            for (int kw5 = 0; kw5 < 5; ++kw5) {
                v8s Bv[4];
                #pragma unroll
                for (int pp = 0; pp < 4; ++pp)
                    Bv[pp] = *(const v8s*)(patchB + (rb0 + pp * PXROW + kw5 + 1) * PIXSTRIDE + laneBoff);

                {
                    const unsigned short* wp = wq + (49 + kh5 * 5 + kw5) * 15360;
                    const v8s A0 = *(const v8s*)(wp);
                    const v8s A1 = *(const v8s*)(wp + 512);
                    const v8s A2 = *(const v8s*)(wp + 1024);
                    #pragma unroll
                    for (int pp = 0; pp < 4; ++pp) {
                        acc2[0][pp] = __builtin_amdgcn_mfma_f32_16x16x32_bf16(A0, Bv[pp], acc2[0][pp], 0, 0, 0);
                        acc2[1][pp] = __builtin_amdgcn_mfma_f32_16x16x32_bf16(A1, Bv[pp], acc2[1][pp], 0, 0, 0);
                        acc2[2][pp] = __builtin_amdgcn_mfma_f32_16x16x32_bf16(A2, Bv[pp], acc2[2][pp], 0, 0, 0);
                    }
                }
                if (kh5 >= 1 && kh5 <= 3 && kw5 >= 1 && kw5 <= 3) {
                    const unsigned short* wp = wq + (74 + (kh5 - 1) * 3 + (kw5 - 1)) * 15360;
                    const v8s A0 = *(const v8s*)(wp);
                    const v8s A1 = *(const v8s*)(wp + 512);
                    const v8s A2 = *(const v8s*)(wp + 1024);
                    #pragma unroll
                    for (int pp = 0; pp < 4; ++pp) {
                        acc1[0][pp] = __builtin_amdgcn_mfma_f32_16x16x32_bf16(A0, Bv[pp], acc1[0][pp], 0, 0, 0);
                        acc1[1][pp] = __builtin_amdgcn_mfma_f32_16x16x32_bf16(A1, Bv[pp], acc1[1][pp], 0, 0, 0);
                        acc1[2][pp] = __builtin_amdgcn_mfma_f32_16x16x32_bf16(A2, Bv[pp], acc1[2][pp], 0, 0, 0);
                    }
                }
            }
        }
    }

    // epilogue: combine with y3, write add/mx packed bf16
    #pragma unroll
    for (int dt = 0; dt < 3; ++dt) {
        #pragma unroll
        for (int reg = 0; reg < 4; ++reg) {
            const int d = dhalf * 48 + dt * 16 + hi * 4 + reg;
            const float i1 = bns[d*4+0], c1 = bns[d*4+1];
            const float i2 = bns[d*4+2], c2 = bns[d*4+3];
            unsigned short* pl = (unsigned short*)(outp + (((size_t)b * D_ + d) << 12));
            #pragma unroll
            for (int pp = 0; pp < 4; ++pp) {
                const int idx = ((h0 + ptb + pp) << 6) + w0 + lo;
                const float y1 = fmaxf(0.f, fmaf(acc1[dt][pp][reg], i1, c1));
                const float y2 = fmaxf(0.f, fmaf(acc2[dt][pp][reg], i2, c2));
                union { unsigned short u; } yu{pl[4096 + idx]};
                union { unsigned int u; float f; } yc{(unsigned int)yu.u << 16};
                const float y3 = yc.f;
                const float av = y1 + y2 + y3;
                const float mv = fmaxf(y1, fmaxf(y2, y3));
                pl[idx]        = f2bf(av);
                pl[4096 + idx] = f2bf(mv);
            }
        }
    }
}

// ---------------------------------------------------------------------------
// Kernel B: per-plane 3x3 conv over [add; max] with avg folded (unchanged).
// ---------------------------------------------------------------------------
__global__ __launch_bounds__(256) void fuse_kernel(
    const float* __restrict__ wf, float* __restrict__ out)
{
    const int p = blockIdx.x;      // plane = b*96 + d
    const int t = threadIdx.x;
    __shared__ float sa[66 * 66];
    __shared__ float sm[66 * 66];
    const bf16* base = (const bf16*)(out + ((size_t)p << 12));

    for (int i = t; i < 66 * 66; i += 256) {
        const int c = i % 66, r = i / 66;
        const int gh = r - 1, gw = c - 1;
        float va = 0.f, vm = 0.f;
        if (gh >= 0 && gh < 64 && gw >= 0 && gw < 64) {
            va = __bfloat162float(base[(gh << 6) + gw]);
            vm = __bfloat162float(base[4096 + (gh << 6) + gw]);
        }
        sa[i] = va; sm[i] = vm;
    }

    float wa[9], wm[9];
    #pragma unroll
    for (int j = 0; j < 9; ++j) {
        wa[j] = wf[j] + wf[9 + j] * (1.f / 3.f);
        wm[j] = wf[18 + j];
    }
    __syncthreads();

    float* op = out + ((size_t)p << 12);
    for (int i = t; i < 4096; i += 256) {
        const int h = i >> 6, w = i & 63;
        float acc = 0.f;
        #pragma unroll
        for (int kh = 0; kh < 3; ++kh) {
            #pragma unroll
            for (int kw = 0; kw < 3; ++kw) {
                acc = fmaf(sa[(h + kh) * 66 + (w + kw)], wa[kh * 3 + kw], acc);
                acc = fmaf(sm[(h + kh) * 66 + (w + kw)], wm[kh * 3 + kw], acc);
            }
        }
        op[i] = acc;
    }
}

extern "C" void kernel_launch(void* const* d_in, const int* in_sizes, int n_in,
                              void* d_out, int out_size, void* d_ws, size_t ws_size,
                              hipStream_t stream)
{
    const float* x   = (const float*)d_in[0];
    const float* w1  = (const float*)d_in[1];
    const float* b1  = (const float*)d_in[2];
    const float* g1  = (const float*)d_in[3];
    const float* be1 = (const float*)d_in[4];
    const float* m1  = (const float*)d_in[5];
    const float* v1  = (const float*)d_in[6];
    const float* w2  = (const float*)d_in[7];
    const float* b2  = (const float*)d_in[8];
    const float* g2  = (const float*)d_in[9];
    const float* be2 = (const float*)d_in[10];
    const float* m2  = (const float*)d_in[11];
    const float* v2  = (const float*)d_in[12];
    const float* w3  = (const float*)d_in[13];
    const float* b3  = (const float*)d_in[14];
    const float* g3  = (const float*)d_in[15];
    const float* be3 = (const float*)d_in[16];
    const float* m3  = (const float*)d_in[17];
    const float* v3  = (const float*)d_in[18];
    const float* wf  = (const float*)d_in[19];
    float* out = (float*)d_out;

    // d_ws: packed bf16 weights only (2.55 MB, proven safe in rounds 4-5)
    unsigned short* wpack = (unsigned short*)d_ws;

    prep_weights<<<(WPACK_ELEMS + 255) / 256, 256, 0, stream>>>(w1, w2, w3, wpack);

    dim3 gridA(16, B_);   // 16 spatial tiles x 32 batch
    k7_conv<<<gridA, 512, 0, stream>>>(x, wpack, b3, g3, be3, m3, v3, out);
    k53_conv<<<gridA, 512, 0, stream>>>(x, wpack,
                                        b1, g1, be1, m1, v1,
                                        b2, g2, be2, m2, v2, out);

    fuse_kernel<<<B_ * D_, 256, 0, stream>>>(wf, out);
}